// Round 1
// baseline (573.549 us; speedup 1.0000x reference)
//
#include <hip/hip_runtime.h>

// Problem constants
#define B_N 4096
#define T_N 512
// Output layout (floats): final (B,T,2) | fwd_out (B,2) | noise (B,T,1)
#define FWD_OFF   (B_N * T_N * 2)        // 4194304
#define NOISE_OFF (FWD_OFF + B_N * 2)    // 4202496
// Workspace layout (floats): encoder final states
#define WS_H0 0
#define WS_C0 (B_N * 4)
#define WS_H1 (B_N * 8)
#define WS_C1 (B_N * 12)

__device__ __forceinline__ float sigf(float v) {
    // 1/(1+e^-v); large |v| saturates correctly via inf/0
    return __builtin_amdgcn_rcpf(1.0f + __expf(-v));
}
__device__ __forceinline__ float tanhf_(float v) {
    // 1 - 2/(e^{2v}+1)
    return 1.0f - 2.0f * __builtin_amdgcn_rcpf(1.0f + __expf(2.0f * v));
}

// ---------------- Encoder: 4 lanes per batch element (unit-major, H=4) ----------------
__global__ __launch_bounds__(256, 1) void enc_kernel(
    const float* __restrict__ x,
    const float* __restrict__ Wih0, const float* __restrict__ Whh0,
    const float* __restrict__ bih0, const float* __restrict__ bhh0,
    const float* __restrict__ Wih1, const float* __restrict__ Whh1,
    const float* __restrict__ bih1, const float* __restrict__ bhh1,
    const float* __restrict__ fcW, const float* __restrict__ fcb,
    float* __restrict__ out, float* __restrict__ ws)
{
    const int tid = blockIdx.x * 256 + threadIdx.x;
    const int b = tid >> 2;   // batch element
    const int u = tid & 3;    // hidden unit

    // Per-lane weights: gate rows r = k*4+u for k in {i,f,g,o}
    float wih0r[4], b0r[4], b1r[4];
    float whh0r[4][4], wih1r[4][4], whh1r[4][4];
#pragma unroll
    for (int k = 0; k < 4; ++k) {
        const int r = k * 4 + u;
        wih0r[k] = Wih0[r];
        b0r[k] = bih0[r] + bhh0[r];
        b1r[k] = bih1[r] + bhh1[r];
#pragma unroll
        for (int j = 0; j < 4; ++j) {
            whh0r[k][j] = Whh0[r * 4 + j];
            wih1r[k][j] = Wih1[r * 4 + j];
            whh1r[k][j] = Whh1[r * 4 + j];
        }
    }

    float h0v[4] = {0.f, 0.f, 0.f, 0.f};
    float h1v[4] = {0.f, 0.f, 0.f, 0.f};
    float c0 = 0.f, c1 = 0.f, h0u = 0.f, h1u = 0.f;

    const float* xb = x + (long)b * T_N;
    float xc = xb[0];

    for (int t = 0; t < T_N; ++t) {
        float xn = xb[(t < T_N - 1) ? (t + 1) : t];  // prefetch next step's input

        // L1 partial from previous h1 (independent of L0 chain -> ILP)
        float p1[4];
#pragma unroll
        for (int k = 0; k < 4; ++k) {
            p1[k] = b1r[k];
#pragma unroll
            for (int j = 0; j < 4; ++j) p1[k] = fmaf(whh1r[k][j], h1v[j], p1[k]);
        }

        // L0 gates
        float g[4];
#pragma unroll
        for (int k = 0; k < 4; ++k) {
            g[k] = fmaf(wih0r[k], xc, b0r[k]);
#pragma unroll
            for (int j = 0; j < 4; ++j) g[k] = fmaf(whh0r[k][j], h0v[j], g[k]);
        }
        float iv = sigf(g[0]), fv = sigf(g[1]), gv = tanhf_(g[2]), ov = sigf(g[3]);
        c0 = fmaf(fv, c0, iv * gv);
        h0u = ov * tanhf_(c0);
#pragma unroll
        for (int j = 0; j < 4; ++j) h0v[j] = __shfl(h0u, j, 4);

        // L1 gates
#pragma unroll
        for (int k = 0; k < 4; ++k) {
#pragma unroll
            for (int j = 0; j < 4; ++j) p1[k] = fmaf(wih1r[k][j], h0v[j], p1[k]);
        }
        iv = sigf(p1[0]); fv = sigf(p1[1]); gv = tanhf_(p1[2]); ov = sigf(p1[3]);
        c1 = fmaf(fv, c1, iv * gv);
        h1u = ov * tanhf_(c1);
#pragma unroll
        for (int j = 0; j < 4; ++j) h1v[j] = __shfl(h1u, j, 4);

        xc = xn;
    }

    // Final states for the decoder
    ws[WS_H0 + b * 4 + u] = h0u;
    ws[WS_C0 + b * 4 + u] = c0;
    ws[WS_H1 + b * 4 + u] = h1u;
    ws[WS_C1 + b * 4 + u] = c1;

    // fwd_out = h1 @ fc_W.T + fc_b  (2 outputs, lanes 0/1)
    if (u < 2) {
        float fw = fcb[u];
#pragma unroll
        for (int j = 0; j < 4; ++j) fw = fmaf(fcW[u * 4 + j], h1v[j], fw);
        out[FWD_OFF + b * 2 + u] = fw;
    }
}

// ---------------- Decoder: 16 lanes per batch element (unit-major, H=10) ----------------
__global__ __launch_bounds__(256, 1) void dec_kernel(
    const float* __restrict__ Wih0, const float* __restrict__ Whh0,
    const float* __restrict__ bih0, const float* __restrict__ bhh0,
    const float* __restrict__ Wih1, const float* __restrict__ Whh1,
    const float* __restrict__ bih1, const float* __restrict__ bhh1,
    const float* __restrict__ outW, const float* __restrict__ outb,
    float* __restrict__ out, const float* __restrict__ ws)
{
    const int tid = blockIdx.x * 256 + threadIdx.x;
    const int b = tid >> 4;        // batch element
    const int u = tid & 15;        // unit (0..9 active; 10..15 shadow unit 9)
    const int uc = (u < 10) ? u : 9;

    float wih0r[4], b0r[4], b1r[4];
    float whh0r[4][10], wih1r[4][10], whh1r[4][10];
#pragma unroll
    for (int k = 0; k < 4; ++k) {
        const int r = k * 10 + uc;
        wih0r[k] = Wih0[r];
        b0r[k] = bih0[r] + bhh0[r];
        b1r[k] = bih1[r] + bhh1[r];
#pragma unroll
        for (int j = 0; j < 10; ++j) {
            whh0r[k][j] = Whh0[r * 10 + j];
            wih1r[k][j] = Wih1[r * 10 + j];
            whh1r[k][j] = Whh1[r * 10 + j];
        }
    }
    float outw[10];
#pragma unroll
    for (int j = 0; j < 10; ++j) outw[j] = outW[j];
    const float outb0 = outb[0];
    const float fwd0 = out[FWD_OFF + b * 2 + 0];
    const float fwd1 = out[FWD_OFF + b * 2 + 1];

    // Initial states: encoder finals padded 4 -> 10 with zeros
    float h0v[10], h1v[10];
#pragma unroll
    for (int j = 0; j < 10; ++j) {
        h0v[j] = (j < 4) ? ws[WS_H0 + b * 4 + j] : 0.f;
        h1v[j] = (j < 4) ? ws[WS_H1 + b * 4 + j] : 0.f;
    }
    float c0 = (u < 4) ? ws[WS_C0 + b * 4 + u] : 0.f;
    float c1 = (u < 4) ? ws[WS_C1 + b * 4 + u] : 0.f;

    float my_noise = 0.f;

    for (int t = 0; t < T_N; ++t) {
        const float inp = h1v[0];

        // L1 partial from previous h1 (independent of L0 chain)
        float p1[4];
#pragma unroll
        for (int k = 0; k < 4; ++k) {
            p1[k] = b1r[k];
#pragma unroll
            for (int j = 0; j < 10; ++j) p1[k] = fmaf(whh1r[k][j], h1v[j], p1[k]);
        }

        // L0 gates for this unit
        float g[4];
#pragma unroll
        for (int k = 0; k < 4; ++k) {
            g[k] = fmaf(wih0r[k], inp, b0r[k]);
#pragma unroll
            for (int j = 0; j < 10; ++j) g[k] = fmaf(whh0r[k][j], h0v[j], g[k]);
        }
        float iv = sigf(g[0]), fv = sigf(g[1]), gv = tanhf_(g[2]), ov = sigf(g[3]);
        c0 = fmaf(fv, c0, iv * gv);
        const float h0u = ov * tanhf_(c0);
#pragma unroll
        for (int j = 0; j < 10; ++j) h0v[j] = __shfl(h0u, j, 16);

        // L1 gates
#pragma unroll
        for (int k = 0; k < 4; ++k) {
#pragma unroll
            for (int j = 0; j < 10; ++j) p1[k] = fmaf(wih1r[k][j], h0v[j], p1[k]);
        }
        iv = sigf(p1[0]); fv = sigf(p1[1]); gv = tanhf_(p1[2]); ov = sigf(p1[3]);
        c1 = fmaf(fv, c1, iv * gv);
        const float h1u = ov * tanhf_(c1);
#pragma unroll
        for (int j = 0; j < 10; ++j) h1v[j] = __shfl(h1u, j, 16);

        // noise_t = dec_out . out_W + out_b (replicated on all 16 lanes)
        float nz = outb0;
#pragma unroll
        for (int j = 0; j < 10; ++j) nz = fmaf(outw[j], h1v[j], nz);

        // lane u keeps the t with t%16==u; flush coalesced every 16 steps
        my_noise = ((t & 15) == u) ? nz : my_noise;
        if ((t & 15) == 15) {
            const int idx = b * T_N + (t - 15) + u;
            out[NOISE_OFF + idx] = my_noise;
            out[2 * idx + 0] = my_noise + fwd0;
            out[2 * idx + 1] = my_noise + fwd1;
        }
    }
}

extern "C" void kernel_launch(void* const* d_in, const int* in_sizes, int n_in,
                              void* d_out, int out_size, void* d_ws, size_t ws_size,
                              hipStream_t stream) {
    const float* x        = (const float*)d_in[0];
    // d_in[1] = context (unused by the reference)
    const float* eWih0 = (const float*)d_in[2];
    const float* eWhh0 = (const float*)d_in[3];
    const float* ebih0 = (const float*)d_in[4];
    const float* ebhh0 = (const float*)d_in[5];
    const float* eWih1 = (const float*)d_in[6];
    const float* eWhh1 = (const float*)d_in[7];
    const float* ebih1 = (const float*)d_in[8];
    const float* ebhh1 = (const float*)d_in[9];
    const float* dWih0 = (const float*)d_in[10];
    const float* dWhh0 = (const float*)d_in[11];
    const float* dbih0 = (const float*)d_in[12];
    const float* dbhh0 = (const float*)d_in[13];
    const float* dWih1 = (const float*)d_in[14];
    const float* dWhh1 = (const float*)d_in[15];
    const float* dbih1 = (const float*)d_in[16];
    const float* dbhh1 = (const float*)d_in[17];
    const float* fcW   = (const float*)d_in[18];
    const float* fcb   = (const float*)d_in[19];
    const float* outW  = (const float*)d_in[20];
    const float* outb  = (const float*)d_in[21];

    float* out = (float*)d_out;
    float* ws  = (float*)d_ws;

    // Encoder: 4096 elems x 4 lanes = 16384 threads
    enc_kernel<<<dim3((B_N * 4) / 256), dim3(256), 0, stream>>>(
        x, eWih0, eWhh0, ebih0, ebhh0, eWih1, eWhh1, ebih1, ebhh1,
        fcW, fcb, out, ws);

    // Decoder: 4096 elems x 16 lanes = 65536 threads
    dec_kernel<<<dim3((B_N * 16) / 256), dim3(256), 0, stream>>>(
        dWih0, dWhh0, dbih0, dbhh0, dWih1, dWhh1, dbih1, dbhh1,
        outW, outb, out, ws);
}